// Round 13
// baseline (396.392 us; speedup 1.0000x reference)
//
#include <hip/hip_runtime.h>
#include <stdint.h>

// ---------------------------------------------------------------------------
// TransformerBlock: B=32, L=512, D=256, H=4.
// Inputs fp32 (dict order); OUTPUT fp32.
// bf16 MFMA GEMMs + fused flash attention (r10 body: uniform unrolled
// staging, no causal branches — measured 141us; r11/r12 causal-skip variants
// regressed to ~172us by breaking the async pipeline schedule).
// ws = 59 + 5*CB MiB (CB=32 -> single chunk at ws=256MiB).
// ---------------------------------------------------------------------------
#define SEQ   512
#define DM    256
#define NB    32
#define NH    4
#define HD    (NH * DM)           // 1024
#define PE_MASK (SEQ * DM - 1)    // 131071
#define NEGV  (-4294967295.0f)

typedef __attribute__((ext_vector_type(8))) short short8;   // 8 x bf16
typedef __attribute__((ext_vector_type(4))) float f32x4;    // MFMA accumulator

#if defined(__has_builtin)
#if __has_builtin(__builtin_amdgcn_global_load_lds)
#define HAS_ASYNC 1
#endif
#endif
#ifndef HAS_ASYNC
#define HAS_ASYNC 0
#endif

__device__ __forceinline__ float b2f(unsigned short u) {
    return __uint_as_float(((uint32_t)u) << 16);
}
__device__ __forceinline__ unsigned short f2b(float f) {
    uint32_t u = __float_as_uint(f);
    u += 0x7fffu + ((u >> 16) & 1u);   // RNE
    return (unsigned short)(u >> 16);
}

// ---------------------------------------------------------------------------
// Canonicalize mask to int32 (auto-detect uint8 / int32 / int64) — r7-green.
// ---------------------------------------------------------------------------
__global__ __launch_bounds__(256) void mask_canon(
    const unsigned char* __restrict__ raw, int* __restrict__ canon)
{
    __shared__ int enc_byte, enc_odd;
    int tid = threadIdx.x;
    if (tid == 0) { enc_byte = 0; enc_odd = 0; }
    __syncthreads();
    if (tid < 255 && raw[tid * 4 + 1]) atomicOr(&enc_byte, 1);
    if (tid < 128 && ((const int*)raw)[tid * 2 + 1]) atomicOr(&enc_odd, 1);
    __syncthreads();
    int i = blockIdx.x * 256 + tid;
    int v;
    if (enc_byte)      v = (raw[i] != 0);
    else if (enc_odd)  v = (((const int*)raw)[i] != 0);
    else               v = ((((const int*)raw)[i * 2] | ((const int*)raw)[i * 2 + 1]) != 0);
    canon[i] = v;
}

// ---------------------------------------------------------------------------
// addpe3: Q/K/V + pe -> bf16, one dispatch (seg = blk>>12).
// ---------------------------------------------------------------------------
__global__ __launch_bounds__(256) void addpe3(
    const float* __restrict__ Q, const float* __restrict__ K,
    const float* __restrict__ V, const float* __restrict__ pe,
    unsigned short* __restrict__ Qp, unsigned short* __restrict__ Kp,
    unsigned short* __restrict__ Vp)
{
    int blk = blockIdx.x;                  // 0..12287
    int seg = blk >> 12;
    const float* X = (seg == 0) ? Q : (seg == 1) ? K : V;
    unsigned short* O = (seg == 0) ? Qp : (seg == 1) ? Kp : Vp;
    long i = (long)((blk & 4095) * 256 + threadIdx.x) * 4;
    float4 x = *reinterpret_cast<const float4*>(X + i);
    float4 p = *reinterpret_cast<const float4*>(pe + (i & PE_MASK));
    ushort4 o;
    o.x = f2b(x.x + p.x); o.y = f2b(x.y + p.y);
    o.z = f2b(x.z + p.z); o.w = f2b(x.w + p.w);
    *reinterpret_cast<ushort4*>(O + i) = o;
}

// ---------------------------------------------------------------------------
// conv2: w1,w2 fp32 -> bf16, one dispatch (128 blocks).
// ---------------------------------------------------------------------------
__global__ __launch_bounds__(256) void conv2(
    const float* __restrict__ w1, const float* __restrict__ w2,
    unsigned short* __restrict__ o1, unsigned short* __restrict__ o2)
{
    int blk = blockIdx.x;
    const float* in = (blk < 64) ? w1 : w2;
    unsigned short* out = (blk < 64) ? o1 : o2;
    long i = (long)((blk & 63) * 256 + threadIdx.x) * 4;
    float4 x = *reinterpret_cast<const float4*>(in + i);
    ushort4 o;
    o.x = f2b(x.x); o.y = f2b(x.y); o.z = f2b(x.z); o.w = f2b(x.w);
    *reinterpret_cast<ushort4*>(out + i) = o;
}

// ---------------------------------------------------------------------------
// Transpose fp32 -> bf16 (3-input z-select): out[c][r] = bf16(in[r][c]).
// ---------------------------------------------------------------------------
__global__ __launch_bounds__(256) void transpose_f2b3(
    const float* __restrict__ in0, const float* __restrict__ in1,
    const float* __restrict__ in2, unsigned short* __restrict__ out,
    int ldin, int ldout, long outStride)
{
    int z = blockIdx.z;
    const float* in = (z == 0) ? in0 : (z == 1) ? in1 : in2;
    unsigned short* op = out + z * outStride;
    __shared__ unsigned short tile[32][33];
    int r0 = blockIdx.y * 32, c0 = blockIdx.x * 32;
    int i = threadIdx.x >> 3;
    int j = (threadIdx.x & 7) * 4;
    float4 v = *reinterpret_cast<const float4*>(in + (long)(r0 + i) * ldin + c0 + j);
    tile[i][j + 0] = f2b(v.x); tile[i][j + 1] = f2b(v.y);
    tile[i][j + 2] = f2b(v.z); tile[i][j + 3] = f2b(v.w);
    __syncthreads();
    ushort4 w;
    w.x = tile[j + 0][i]; w.y = tile[j + 1][i]; w.z = tile[j + 2][i]; w.w = tile[j + 3][i];
    *reinterpret_cast<ushort4*>(op + (long)(c0 + i) * ldout + r0 + j) = w;
}

__global__ __launch_bounds__(256) void transpose_f2b(
    const float* __restrict__ in, unsigned short* __restrict__ out,
    int ldin, int ldout)
{
    __shared__ unsigned short tile[32][33];
    int r0 = blockIdx.y * 32, c0 = blockIdx.x * 32;
    int i = threadIdx.x >> 3;
    int j = (threadIdx.x & 7) * 4;
    float4 v = *reinterpret_cast<const float4*>(in + (long)(r0 + i) * ldin + c0 + j);
    tile[i][j + 0] = f2b(v.x); tile[i][j + 1] = f2b(v.y);
    tile[i][j + 2] = f2b(v.z); tile[i][j + 3] = f2b(v.w);
    __syncthreads();
    ushort4 w;
    w.x = tile[j + 0][i]; w.y = tile[j + 1][i]; w.z = tile[j + 2][i]; w.w = tile[j + 3][i];
    *reinterpret_cast<ushort4*>(out + (long)(c0 + i) * ldout + r0 + j) = w;
}

// ---------------------------------------------------------------------------
// Batched bf16 transpose (per-head V): out[c][r] = in[r][c]
// ---------------------------------------------------------------------------
__global__ __launch_bounds__(256) void transpose_bf16(
    const unsigned short* __restrict__ in, unsigned short* __restrict__ out,
    int ldin, int ldout, long sInB, long sInH, long sOutB, long sOutH, int Hdiv)
{
    int z = blockIdx.z; int b = z / Hdiv; int h = z % Hdiv;
    const unsigned short* ip = in + b * sInB + h * sInH;
    unsigned short* op = out + b * sOutB + h * sOutH;
    __shared__ unsigned short tile[32][33];
    int r0 = blockIdx.y * 32, c0 = blockIdx.x * 32;
    int i = threadIdx.x >> 3;
    int j = (threadIdx.x & 7) * 4;
    ushort4 v = *reinterpret_cast<const ushort4*>(ip + (long)(r0 + i) * ldin + c0 + j);
    tile[i][j + 0] = v.x; tile[i][j + 1] = v.y; tile[i][j + 2] = v.z; tile[i][j + 3] = v.w;
    __syncthreads();
    ushort4 w;
    w.x = tile[j + 0][i]; w.y = tile[j + 1][i]; w.z = tile[j + 2][i]; w.w = tile[j + 3][i];
    *reinterpret_cast<ushort4*>(op + (long)(c0 + i) * ldout + r0 + j) = w;
}

// ---------------------------------------------------------------------------
// Pure-bf16 MFMA GEMM (r9-green): C = scale*A.Bt (+bias, relu), 128x128 tile,
// global_load_lds width-16 staging. Batched via blockIdx.z.
// ---------------------------------------------------------------------------
template<bool BIAS, bool RELU, bool OUTBF16>
__global__ __launch_bounds__(256) void gemm_bt(
    const unsigned short* __restrict__ A, int lda,
    const unsigned short* __restrict__ B, int ldb,
    void* __restrict__ Cv, int ldc,
    const float* __restrict__ bias, float scale, int K, int Hdiv,
    long sAb, long sAh, long sAz,
    long sBb, long sBh, long sBz,
    long sCb, long sCh, long sCz)
{
    const int m0 = blockIdx.y * 128;
    const int n0 = blockIdx.x * 128;
    int z  = blockIdx.z;
    int bb = z / Hdiv, hh = z % Hdiv;
    const unsigned short* Ab = A + bb * sAb + hh * sAh + (long)z * sAz;
    const unsigned short* Bb = B + bb * sBb + hh * sBh + (long)z * sBz;
    long coff = bb * sCb + hh * sCh + (long)z * sCz;

    __shared__ unsigned short As[128 * 32];
    __shared__ unsigned short Bs[128 * 32];

    const int tid  = threadIdx.x;
    const int lane = tid & 63;
    const int wave = tid >> 6;
    const int wm   = (wave >> 1) * 64;
    const int wn   = (wave & 1) * 64;
    const int lm   = lane & 15;
    const int kq   = (lane >> 4) * 8;

    f32x4 acc[4][4] = {};

    for (int k0 = 0; k0 < K; k0 += 32) {
#pragma unroll
        for (int it = 0; it < 2; ++it) {
            int id = tid + it * 256;
            int r  = id >> 2;
            int c8 = (id & 3) * 8;
            const unsigned short* gA = Ab + (long)(m0 + r) * lda + k0 + c8;
            const unsigned short* gB = Bb + (long)(n0 + r) * ldb + k0 + c8;
#if HAS_ASYNC
            unsigned short* lA = &As[(size_t)(it * 256 + wave * 64) * 8];
            unsigned short* lB = &Bs[(size_t)(it * 256 + wave * 64) * 8];
            __builtin_amdgcn_global_load_lds(
                (const __attribute__((address_space(1))) void*)gA,
                (__attribute__((address_space(3))) void*)lA, 16, 0, 0);
            __builtin_amdgcn_global_load_lds(
                (const __attribute__((address_space(1))) void*)gB,
                (__attribute__((address_space(3))) void*)lB, 16, 0, 0);
#else
            *reinterpret_cast<uint4*>(&As[(size_t)id * 8]) =
                *reinterpret_cast<const uint4*>(gA);
            *reinterpret_cast<uint4*>(&Bs[(size_t)id * 8]) =
                *reinterpret_cast<const uint4*>(gB);
#endif
        }
        __syncthreads();

        short8 af[4], bfr[4];
#pragma unroll
        for (int i = 0; i < 4; ++i)
            af[i] = *reinterpret_cast<const short8*>(&As[(wm + i * 16 + lm) * 32 + kq]);
#pragma unroll
        for (int j = 0; j < 4; ++j)
            bfr[j] = *reinterpret_cast<const short8*>(&Bs[(wn + j * 16 + lm) * 32 + kq]);
#pragma unroll
        for (int i = 0; i < 4; ++i)
#pragma unroll
            for (int j = 0; j < 4; ++j)
                acc[i][j] = __builtin_amdgcn_mfma_f32_16x16x32_bf16(af[i], bfr[j], acc[i][j], 0, 0, 0);
        __syncthreads();
    }

#pragma unroll
    for (int j = 0; j < 4; ++j) {
        int col  = n0 + wn + j * 16 + lm;
        float bv = 0.f;
        if (BIAS) bv = bias[col];
#pragma unroll
        for (int i = 0; i < 4; ++i) {
#pragma unroll
            for (int r = 0; r < 4; ++r) {
                int row = m0 + wm + i * 16 + (lane >> 4) * 4 + r;
                float v = acc[i][j][r] * scale + bv;
                if (RELU) v = fmaxf(v, 0.f);
                long idx = coff + (long)row * ldc + col;
                if (OUTBF16) reinterpret_cast<unsigned short*>(Cv)[idx] = f2b(v);
                else         reinterpret_cast<float*>(Cv)[idx] = v;
            }
        }
    }
}

// ---------------------------------------------------------------------------
// Fused flash attention — r10 body (measured 141us; causal-skip variants
// regressed by breaking the unrolled async staging schedule).
// One bh x 64 q-rows per block; 4 waves x 16 rows.
//  Phase 1: S(16x512/wave, fp32 regs) = scale * Q.K^T  (K LDS-staged, 8 kc).
//  Softmax in regs; all 512 keys computed -> pad-masked rows uniform 1/512.
//  Phase 2: O(16x256) = P.V  (V LDS-staged; P via per-wave LDS, A-layout).
// Layouts m89-verified.
// ---------------------------------------------------------------------------
__global__ __launch_bounds__(256) void flash_attn(
    const unsigned short* __restrict__ Qh,
    const unsigned short* __restrict__ Kh,
    const unsigned short* __restrict__ VhT,
    unsigned short* __restrict__ Vatt,
    const int* __restrict__ maskc, int bh0, float scale)
{
    const int tid  = threadIdx.x;
    const int lane = tid & 63;
    const int wave = tid >> 6;
    const int lm   = lane & 15;
    const int qg   = lane >> 4;
    const int kq   = qg * 8;

    const int z   = blockIdx.z;              // chunk-local bh
    const int b_l = z >> 2, h = z & 3;
    const int m0  = blockIdx.x * 64;         // q-tile base within seq
    const int wq0 = m0 + wave * 16;          // this wave's first q row
    const long qkbase = (long)b_l * SEQ * HD + (long)h * DM;
    const unsigned short* Aq = Qh + qkbase;
    const unsigned short* Ak = Kh + qkbase;
    const unsigned short* Av = VhT + (long)b_l * SEQ * HD + (long)h * SEQ * DM;
    unsigned short* Ov = Vatt + qkbase;
    const int bglob = (bh0 + z) >> 2;

    __shared__ unsigned short Ks[SEQ * 32];                 // 32 KiB (phase 1)
    __shared__ __align__(16) unsigned short Pw[4][16][40];  // 5 KiB, 80B rows

    f32x4 S[32] = {};

    // ---- Phase 1: S = Q.K^T over 8 k-chunks of 32 ----
    for (int kc = 0; kc < 8; ++kc) {
#pragma unroll
        for (int it = 0; it < 8; ++it) {
            int id = tid + it * 256;            // 0..2047 16B-chunks
            const unsigned short* g = Ak + (long)(id >> 2) * HD + kc * 32 + (id & 3) * 8;
#if HAS_ASYNC
            unsigned short* l = &Ks[(size_t)(it * 256 + wave * 64) * 8];
            __builtin_amdgcn_global_load_lds(
                (const __attribute__((address_space(1))) void*)g,
                (__attribute__((address_space(3))) void*)l, 16, 0, 0);
#else
            *reinterpret_cast<uint4*>(&Ks[(size_t)id * 8]) =
                *reinterpret_cast<const uint4*>(g);
#endif
        }
        short8 qf = *reinterpret_cast<const short8*>(
            Aq + (long)(wq0 + lm) * HD + kc * 32 + kq);
        __syncthreads();
#pragma unroll
        for (int nt = 0; nt < 32; ++nt) {
            short8 bf = *reinterpret_cast<const short8*>(&Ks[(nt * 16 + lm) * 32 + kq]);
            S[nt] = __builtin_amdgcn_mfma_f32_16x16x32_bf16(qf, bf, S[nt], 0, 0, 0);
        }
        __syncthreads();
    }

    // ---- Softmax in registers (per lane: 4 rows x 32 col-samples) ----
    int   qrow[4];
    bool  rowm[4];
    float mx[4], sm[4];
#pragma unroll
    for (int r = 0; r < 4; ++r) {
        int q = m0 + wave * 16 + qg * 4 + r;
        qrow[r] = q;
        rowm[r] = maskc[bglob * SEQ + q] != 0;
        mx[r] = -3.4e38f;
    }
#pragma unroll
    for (int nt = 0; nt < 32; ++nt) {
        int k = nt * 16 + lm;
#pragma unroll
        for (int r = 0; r < 4; ++r) {
            float v = S[nt][r] * scale;
            if (k > qrow[r] || rowm[r]) v = NEGV;
            S[nt][r] = v;
            mx[r] = fmaxf(mx[r], v);
        }
    }
#pragma unroll
    for (int r = 0; r < 4; ++r) {
#pragma unroll
        for (int off = 8; off >= 1; off >>= 1)
            mx[r] = fmaxf(mx[r], __shfl_xor(mx[r], off));
        sm[r] = 0.f;
    }
#pragma unroll
    for (int nt = 0; nt < 32; ++nt)
#pragma unroll
        for (int r = 0; r < 4; ++r) {
            float e = __expf(S[nt][r] - mx[r]);
            S[nt][r] = e;
            sm[r] += e;
        }
#pragma unroll
    for (int r = 0; r < 4; ++r) {
#pragma unroll
        for (int off = 8; off >= 1; off >>= 1)
            sm[r] += __shfl_xor(sm[r], off);
        sm[r] = 1.0f / sm[r];
    }
#pragma unroll
    for (int nt = 0; nt < 32; ++nt)
#pragma unroll
        for (int r = 0; r < 4; ++r) S[nt][r] *= sm[r];

    // ---- Phase 2: O = P.V over 16 key-chunks of 32 ----
    f32x4 O[16] = {};
    unsigned short* Vs = Ks;                 // reuse first 16 KiB
    for (int kc2 = 0; kc2 < 16; ++kc2) {
#pragma unroll
        for (int it = 0; it < 4; ++it) {
            int id = tid + it * 256;            // 256 d-rows x 32 keys
            const unsigned short* g = Av + (long)(id >> 2) * SEQ + kc2 * 32 + (id & 3) * 8;
#if HAS_ASYNC
            unsigned short* l = &Vs[(size_t)(it * 256 + wave * 64) * 8];
            __builtin_amdgcn_global_load_lds(
                (const __attribute__((address_space(1))) void*)g,
                (__attribute__((address_space(3))) void*)l, 16, 0, 0);
#else
            *reinterpret_cast<uint4*>(&Vs[(size_t)id * 8]) =
                *reinterpret_cast<const uint4*>(g);
#endif
        }
        // P chunk (32 keys) C-layout -> per-wave LDS rows (A-layout source)
#pragma unroll
        for (int t = 0; t < 2; ++t) {
            int nt = kc2 * 2 + t;
#pragma unroll
            for (int r = 0; r < 4; ++r)
                Pw[wave][qg * 4 + r][t * 16 + lm] = f2b(S[nt][r]);
        }
        __syncthreads();
        short8 pf = *reinterpret_cast<const short8*>(&Pw[wave][lm][kq]);
#pragma unroll
        for (int nt2 = 0; nt2 < 16; ++nt2) {
            short8 vf = *reinterpret_cast<const short8*>(&Vs[(nt2 * 16 + lm) * 32 + kq]);
            O[nt2] = __builtin_amdgcn_mfma_f32_16x16x32_bf16(pf, vf, O[nt2], 0, 0, 0);
        }
        __syncthreads();
    }

    // ---- epilogue: O C-layout -> Vatt[b][q][h*256+d] bf16 ----
#pragma unroll
    for (int nt2 = 0; nt2 < 16; ++nt2) {
#pragma unroll
        for (int r = 0; r < 4; ++r) {
            int l = wq0 + qg * 4 + r;
            Ov[(long)l * HD + nt2 * 16 + lm] = f2b(O[nt2][r]);
        }
    }
}

// ---------------------------------------------------------------------------
// LN1: x = bf16 AttO + fp32 Q + fp32 pe  ->  fp32 Xf AND bf16 Xb
// ---------------------------------------------------------------------------
__global__ __launch_bounds__(256) void ln1_kernel(
    const unsigned short* __restrict__ AttO, const float* __restrict__ Q,
    const float* __restrict__ pe,
    const float* __restrict__ gamma, const float* __restrict__ beta,
    float* __restrict__ outf, unsigned short* __restrict__ outb)
{
    int row  = blockIdx.x * 4 + (threadIdx.x >> 6);
    int lane = threadIdx.x & 63;
    long base = (long)row * DM + lane * 4;
    ushort4 a = *reinterpret_cast<const ushort4*>(AttO + base);
    float4 qv = *reinterpret_cast<const float4*>(Q + base);
    float4 pv = *reinterpret_cast<const float4*>(pe + (base & PE_MASK));
    float x[4] = {b2f(a.x) + qv.x + pv.x, b2f(a.y) + qv.y + pv.y,
                  b2f(a.z) + qv.z + pv.z, b2f(a.w) + qv.w + pv.w};
    float s = x[0] + x[1] + x[2] + x[3];
#pragma unroll
    for (int off = 32; off > 0; off >>= 1) s += __shfl_xor(s, off);
    float mu = s * (1.0f / DM);
    float vs = 0.f;
#pragma unroll
    for (int t = 0; t < 4; ++t) { float d = x[t] - mu; vs += d * d; }
#pragma unroll
    for (int off = 32; off > 0; off >>= 1) vs += __shfl_xor(vs, off);
    float inv = rsqrtf(vs * (1.0f / DM) + 1e-5f);
    int d0 = lane * 4;
    float4 g = *reinterpret_cast<const float4*>(gamma + d0);
    float4 bt = *reinterpret_cast<const float4*>(beta + d0);
    float4 o;
    o.x = (x[0] - mu) * inv * g.x + bt.x;
    o.y = (x[1] - mu) * inv * g.y + bt.y;
    o.z = (x[2] - mu) * inv * g.z + bt.z;
    o.w = (x[3] - mu) * inv * g.w + bt.w;
    *reinterpret_cast<float4*>(outf + base) = o;
    ushort4 ob;
    ob.x = f2b(o.x); ob.y = f2b(o.y); ob.z = f2b(o.z); ob.w = f2b(o.w);
    *reinterpret_cast<ushort4*>(outb + base) = ob;
}

// ---------------------------------------------------------------------------
// LN2: x = fp32 F + fp32 X  ->  FP32 out
// ---------------------------------------------------------------------------
__global__ __launch_bounds__(256) void ln2_kernel(
    const float* __restrict__ F, const float* __restrict__ X,
    const float* __restrict__ gamma, const float* __restrict__ beta,
    float* __restrict__ out)
{
    int row  = blockIdx.x * 4 + (threadIdx.x >> 6);
    int lane = threadIdx.x & 63;
    long base = (long)row * DM + lane * 4;
    float4 a = *reinterpret_cast<const float4*>(F + base);
    float4 c = *reinterpret_cast<const float4*>(X + base);
    float x[4] = {a.x + c.x, a.y + c.y, a.z + c.z, a.w + c.w};
    float s = x[0] + x[1] + x[2] + x[3];
#pragma unroll
    for (int off = 32; off > 0; off >>= 1) s += __shfl_xor(s, off);
    float mu = s * (1.0f / DM);
    float vs = 0.f;
#pragma unroll
    for (int t = 0; t < 4; ++t) { float d = x[t] - mu; vs += d * d; }
#pragma unroll
    for (int off = 32; off > 0; off >>= 1) vs += __shfl_xor(vs, off);
    float inv = rsqrtf(vs * (1.0f / DM) + 1e-5f);
    int d0 = lane * 4;
    float4 g = *reinterpret_cast<const float4*>(gamma + d0);
    float4 bt = *reinterpret_cast<const float4*>(beta + d0);
    float4 o;
    o.x = (x[0] - mu) * inv * g.x + bt.x;
    o.y = (x[1] - mu) * inv * g.y + bt.y;
    o.z = (x[2] - mu) * inv * g.z + bt.z;
    o.w = (x[3] - mu) * inv * g.w + bt.w;
    *reinterpret_cast<float4*>(out + base) = o;
}

// ---------------------------------------------------------------------------
extern "C" void kernel_launch(void* const* d_in, const int* in_sizes, int n_in,
                              void* d_out, int out_size, void* d_ws, size_t ws_size,
                              hipStream_t stream)
{
    const float* Q  = (const float*)d_in[0];
    const float* Ki = (const float*)d_in[1];
    const float* Vi = (const float*)d_in[2];
    const unsigned char* mask_raw = (const unsigned char*)d_in[3];
    const float* pe = (const float*)d_in[4];
    const float* Wq = (const float*)d_in[5];
    const float* Wk = (const float*)d_in[6];
    const float* Wv = (const float*)d_in[7];
    const float* Wo = (const float*)d_in[8];
    const float* w1 = (const float*)d_in[9];
    const float* b1 = (const float*)d_in[10];
    const float* w2 = (const float*)d_in[11];
    const float* b2 = (const float*)d_in[12];
    const float* gamma = (const float*)d_in[13];
    const float* beta  = (const float*)d_in[14];
    float* out = (float*)d_out;

    const size_t MiB = 1048576;
    char* ws = (char*)d_ws;

    // ---- adaptive chunk size: footprint = 59 + max(5*CB, 24) MiB ----
    int CB = 1;
    for (int cb = 32; cb >= 1; cb >>= 1) {
        size_t scr_sz = (size_t)(5 * cb) * MiB;
        if (scr_sz < 24 * MiB) scr_sz = 24 * MiB;
        if ((59 * MiB + scr_sz) <= ws_size) { CB = cb; break; }
    }
    const int NCH = NB / CB;

    // ---- fixed low regions ----
    unsigned short* WqT  = (unsigned short*)(ws);                 // 512 KiB each
    unsigned short* WkT  = WqT + 262144;
    unsigned short* WvT  = WkT + 262144;
    unsigned short* WoT  = WvT + 262144;
    unsigned short* w1b  = (unsigned short*)(ws + 2 * MiB);       // 128 KiB
    unsigned short* w2b  = w1b + 65536;                           // 128 KiB
    int*            maskc = (int*)(ws + 2 * MiB + 262144);        // 64 KiB
    unsigned short* Qp   = (unsigned short*)(ws + 3 * MiB);       // 8 MiB bf16
    unsigned short* Kp   = (unsigned short*)(ws + 11 * MiB);      // 8 MiB
    unsigned short* Vp   = (unsigned short*)(ws + 19 * MiB);      // 8 MiB
    unsigned short* AttO = (unsigned short*)(ws + 27 * MiB);      // 8 MiB
    unsigned short* Xb   = (unsigned short*)(ws + 35 * MiB);      // 8 MiB
    float*          Xf   = (float*)(ws + 43 * MiB);               // 16 MiB
    char*           scr  = ws + 59 * MiB;
    // chunk scratch (CB MiB each)
    unsigned short* Qh   = (unsigned short*)(scr);
    unsigned short* Kh   = (unsigned short*)(scr + (size_t)CB * MiB);
    unsigned short* Vh   = (unsigned short*)(scr + (size_t)2 * CB * MiB);
    unsigned short* VhT  = (unsigned short*)(scr + (size_t)3 * CB * MiB);
    unsigned short* Vatt = (unsigned short*)(scr + (size_t)4 * CB * MiB);
    // tail aliases over scratch (chunk buffers dead by then)
    unsigned short* H1   = (unsigned short*)(scr);                // 8 MiB bf16
    float*          Ff   = (float*)(scr + 8 * MiB);               // 16 MiB fp32

    const float scale = (float)(1.0 / (16.0 + 1e-6));
    const long CROWS = (long)CB * SEQ;
    const long CBELT = (long)CB * MiB / 2;     // chunk-buffer stride, elements

    // 0. prep (merged): mask, weight transposes/conversions, fused PE-add
    mask_canon<<<64, 256, 0, stream>>>(mask_raw, maskc);
    transpose_f2b3<<<dim3(32, 8, 3), 256, 0, stream>>>(Wq, Wk, Wv, WqT, HD, DM, 262144);
    transpose_f2b<<<dim3(8, 32, 1), 256, 0, stream>>>(Wo, WoT, DM, HD);
    conv2<<<128, 256, 0, stream>>>(w1, w2, w1b, w2b);
    addpe3<<<12288, 256, 0, stream>>>(Q, Ki, Vi, pe, Qp, Kp, Vp);

    // 1. attention in NCH chunks of CB batches
    for (int c = 0; c < NCH; ++c) {
        const long r0   = (long)c * CROWS;
        const int  bh0  = c * CB * NH;
        const int  gy   = (int)(CROWS / 128);
        const int  nbh  = CB * NH;

        // all 3 projections in ONE dispatch (z=0:Q, 1:K, 2:V)
        gemm_bt<false, false, true><<<dim3(8, gy, 3), 256, 0, stream>>>(
            Qp + r0 * DM, DM, WqT, DM, Qh, HD, nullptr, 1.f, DM,
            1, 4194304, 0, 0, 262144, 0, 0, CBELT, 0, 0);

        // per-head V transpose: VhT[bl][h][d][l] = Vh[bl][l][h*256+d]
        transpose_bf16<<<dim3(8, 16, CB * NH), 256, 0, stream>>>(
            Vh, VhT, HD, SEQ, (long)SEQ * HD, DM, (long)SEQ * HD, (long)SEQ * DM, NH);

        // fused attention (r10 body)
        flash_attn<<<dim3(8, 1, nbh), 256, 0, stream>>>(
            Qh, Kh, VhT, Vatt, maskc, bh0, scale);

        // output projection for this chunk -> AttO rows [r0, r0+CROWS)
        gemm_bt<false, false, true><<<dim3(2, gy, 1), 256, 0, stream>>>(
            Vatt, HD, WoT, HD, AttO + r0 * DM, DM, nullptr, 1.f, HD,
            1, 0,0,0, 0,0,0, 0,0,0);
    }

    // 2. LN1: X = LN(Q + pe + AttO) -> fp32 Xf + bf16 Xb
    ln1_kernel<<<4096, 256, 0, stream>>>(AttO, Q, pe, gamma, beta, Xf, Xb);

    // 3. FFN1: H1 = relu(Xb @ w1^T + b1) -> bf16
    gemm_bt<true, true, true><<<dim3(2, 128, 1), 256, 0, stream>>>(
        Xb, DM, w1b, DM, H1, DM, b1, 1.f, DM, 1, 0,0,0, 0,0,0, 0,0,0);
    // 4. FFN2: F = H1 @ w2^T + b2 -> fp32
    gemm_bt<true, false, false><<<dim3(2, 128, 1), 256, 0, stream>>>(
        H1, DM, w2b, DM, Ff, DM, b2, 1.f, DM, 1, 0,0,0, 0,0,0, 0,0,0);

    // 5. LN2: out = LN(F + X) -> FP32
    ln2_kernel<<<4096, 256, 0, stream>>>(Ff, Xf, gamma, beta, out);
}